// Round 2
// baseline (556.655 us; speedup 1.0000x reference)
//
#include <hip/hip_runtime.h>

#define N_NODES 100000
#define N_EDGES 3200000
#define IN_FEAT 512
#define HID 16
#define SCAN_BLK 512
#define N_SCAN_BLKS ((N_NODES + SCAN_BLK - 1) / SCAN_BLK)   // 196

// ---------------------------------------------------------------------------
// Edge-index dtype hedge (int64 vs int32 storage), probed device-side.
// ---------------------------------------------------------------------------
__global__ void k_detect(const void* ei, int* flag) {
    const int* p = (const int*)ei;
    int t = threadIdx.x;                     // 64 threads = 1 wave
    bool nz = (p[2 * t + 1] != 0);
    unsigned long long m = __ballot(nz);
    if (t == 0) *flag = (m == 0ull) ? 1 : 0; // 1 => int64 storage
}

__device__ __forceinline__ int load_dst(const void* ei, int is64, int e) {
    if (is64) return (int)((const long long*)ei)[(long long)N_EDGES + e];
    return ((const int*)ei)[N_EDGES + e];
}
__device__ __forceinline__ int load_src(const void* ei, int is64, int e) {
    if (is64) return (int)((const long long*)ei)[e];
    return ((const int*)ei)[e];
}

__global__ void k_deg(const void* ei, const int* __restrict__ flag,
                      int* __restrict__ deg) {
    int is64 = *flag;
    int e = blockIdx.x * blockDim.x + threadIdx.x;
    if (e >= N_EDGES) return;
    atomicAdd(&deg[load_dst(ei, is64, e)], 1);
}

// ---- exclusive scan of deg -> off (3 kernels) -----------------------------
__global__ void k_scanA(const int* __restrict__ deg, int* __restrict__ off,
                        int* __restrict__ bsum) {
    __shared__ int s[SCAN_BLK];
    int tid = threadIdx.x;
    int i = blockIdx.x * SCAN_BLK + tid;
    int v = (i < N_NODES) ? deg[i] : 0;
    s[tid] = v;
    __syncthreads();
#pragma unroll
    for (int o = 1; o < SCAN_BLK; o <<= 1) {
        int t = (tid >= o) ? s[tid - o] : 0;
        __syncthreads();
        s[tid] += t;
        __syncthreads();
    }
    if (i < N_NODES) off[i] = s[tid] - v;         // exclusive within block
    if (tid == SCAN_BLK - 1) bsum[blockIdx.x] = s[tid];
}

__global__ void k_scanB(int* __restrict__ bsum) {
    __shared__ int s[256];
    int tid = threadIdx.x;
    int v = (tid < N_SCAN_BLKS) ? bsum[tid] : 0;
    s[tid] = v;
    __syncthreads();
#pragma unroll
    for (int o = 1; o < 256; o <<= 1) {
        int t = (tid >= o) ? s[tid - o] : 0;
        __syncthreads();
        s[tid] += t;
        __syncthreads();
    }
    if (tid < N_SCAN_BLKS) bsum[tid] = s[tid] - v; // exclusive
}

__global__ void k_scanC(int* __restrict__ off, const int* __restrict__ bsum,
                        int* __restrict__ cursor) {
    int i = blockIdx.x * blockDim.x + threadIdx.x;
    if (i >= N_NODES) return;
    int o = off[i] + bsum[i / SCAN_BLK];
    off[i] = o;
    cursor[i] = o;
}

__global__ void k_fill(const void* ei, const int* __restrict__ flag,
                       int* __restrict__ cursor, int* __restrict__ col) {
    int is64 = *flag;
    int e = blockIdx.x * blockDim.x + threadIdx.x;
    if (e >= N_EDGES) return;
    int s = load_src(ei, is64, e);
    int d = load_dst(ei, is64, e);
    int pos = atomicAdd(&cursor[d], 1);
    col[pos] = s;
}

__global__ void k_dinv(const int* __restrict__ deg, float* __restrict__ dinv) {
    int i = blockIdx.x * blockDim.x + threadIdx.x;
    if (i >= N_NODES) return;
    dinv[i] = rsqrtf((float)(deg[i] + 1));   // +1 self-loop; always > 0
}

// xws = (x @ W1) * dinv[row]   (row per lane; W1 reads wave-uniform)
__global__ void k_gemm1(const float* __restrict__ x, const float* __restrict__ W1,
                        const float* __restrict__ dinv, float* __restrict__ xws) {
    int row = blockIdx.x * blockDim.x + threadIdx.x;
    if (row >= N_NODES) return;
    const float4* xr = (const float4*)(x + (size_t)row * IN_FEAT);
    float acc[16];
#pragma unroll
    for (int f = 0; f < 16; ++f) acc[f] = 0.f;

#pragma unroll 1
    for (int k0 = 0; k0 < IN_FEAT; k0 += 16) {  // 16 floats = one 64B line
        float4 v0 = xr[k0 / 4 + 0];
        float4 v1 = xr[k0 / 4 + 1];
        float4 v2 = xr[k0 / 4 + 2];
        float4 v3 = xr[k0 / 4 + 3];
        float xv[16] = {v0.x, v0.y, v0.z, v0.w, v1.x, v1.y, v1.z, v1.w,
                        v2.x, v2.y, v2.z, v2.w, v3.x, v3.y, v3.z, v3.w};
#pragma unroll
        for (int kk = 0; kk < 16; ++kk) {
            const float* wr = W1 + (size_t)(k0 + kk) * HID;  // wave-uniform
#pragma unroll
            for (int f = 0; f < HID; ++f)
                acc[f] = fmaf(xv[kk], wr[f], acc[f]);
        }
    }
    float di = dinv[row];
    float4* xv4 = (float4*)(xws + (size_t)row * HID);
#pragma unroll
    for (int q = 0; q < 4; ++q)
        xv4[q] = make_float4(acc[4 * q] * di, acc[4 * q + 1] * di,
                             acc[4 * q + 2] * di, acc[4 * q + 3] * di);
}

// layer-1 gather: 16 lanes per node; out1 = relu(b1 + dinv[d]*(self + sum))
__global__ void k_gather1(const int* __restrict__ off, const int* __restrict__ deg,
                          const int* __restrict__ col, const float* __restrict__ dinv,
                          const float* __restrict__ xws, const float* __restrict__ b1,
                          float* __restrict__ out1) {
    int t = blockIdx.x * blockDim.x + threadIdx.x;   // exactly N_NODES*16
    int node = t >> 4;
    int f = t & 15;
    int start = off[node];
    int cnt = deg[node];
    float acc = xws[(size_t)node * HID + f];         // self-loop term
    for (int j = 0; j < cnt; j += 16) {
        int myc = (j + f < cnt) ? col[start + j + f] : 0;
        int m = min(16, cnt - j);
        for (int jj = 0; jj < m; ++jj) {
            int s = __shfl(myc, jj, 16);
            acc += xws[(size_t)s * HID + f];
        }
    }
    float v = fmaf(dinv[node], acc, b1[f]);
    out1[(size_t)t] = fmaxf(v, 0.f);                  // fused ReLU
}

// h2s = (relu_out1 @ W2) * dinv
__global__ void k_layer2(const float* __restrict__ out1, const float* __restrict__ W2,
                         const float* __restrict__ dinv, float* __restrict__ h2s) {
    int i = blockIdx.x * blockDim.x + threadIdx.x;
    if (i >= N_NODES) return;
    const float4* hv = (const float4*)(out1 + (size_t)i * HID);
    float g0 = 0.f, g1 = 0.f;
#pragma unroll
    for (int q = 0; q < 4; ++q) {
        float4 v = hv[q];
        g0 = fmaf(v.x, W2[(4 * q + 0) * 2 + 0], g0);
        g1 = fmaf(v.x, W2[(4 * q + 0) * 2 + 1], g1);
        g0 = fmaf(v.y, W2[(4 * q + 1) * 2 + 0], g0);
        g1 = fmaf(v.y, W2[(4 * q + 1) * 2 + 1], g1);
        g0 = fmaf(v.z, W2[(4 * q + 2) * 2 + 0], g0);
        g1 = fmaf(v.z, W2[(4 * q + 2) * 2 + 1], g1);
        g0 = fmaf(v.w, W2[(4 * q + 3) * 2 + 0], g0);
        g1 = fmaf(v.w, W2[(4 * q + 3) * 2 + 1], g1);
    }
    float di = dinv[i];
    ((float2*)h2s)[i] = make_float2(g0 * di, g1 * di);
}

// layer-2 gather + log_softmax: 2 lanes per node
__global__ void k_gather2(const int* __restrict__ off, const int* __restrict__ deg,
                          const int* __restrict__ col, const float* __restrict__ dinv,
                          const float* __restrict__ h2s, const float* __restrict__ b2,
                          float* __restrict__ y) {
    int t = blockIdx.x * blockDim.x + threadIdx.x;
    int node = t >> 1;
    if (node >= N_NODES) return;
    int f = t & 1;
    int start = off[node];
    int cnt = deg[node];
    float acc = h2s[(size_t)node * 2 + f];            // self-loop term
    for (int j = 0; j < cnt; ++j) {
        int c = col[start + j];
        acc += h2s[(size_t)c * 2 + f];
    }
    float v = fmaf(dinv[node], acc, b2[f]);
    float other = __shfl_xor(v, 1);
    float m = fmaxf(v, other);
    float lse = m + logf(expf(v - m) + expf(other - m));
    y[(size_t)t] = v - lse;
}

extern "C" void kernel_launch(void* const* d_in, const int* in_sizes, int n_in,
                              void* d_out, int out_size, void* d_ws, size_t ws_size,
                              hipStream_t stream) {
    const float* x  = (const float*)d_in[0];
    const void*  ei = d_in[1];
    const float* W1 = (const float*)d_in[2];
    const float* b1 = (const float*)d_in[3];
    const float* W2 = (const float*)d_in[4];
    const float* b2 = (const float*)d_in[5];
    float* y = (float*)d_out;

    char* w = (char*)d_ws;
    int*   flag   = (int*)(w + 0);
    int*   deg    = (int*)(w + 1024);        // 400 KB
    int*   off    = (int*)(w + 401408);      // 400 KB
    int*   cursor = (int*)(w + 801792);      // 400 KB
    int*   bsum   = (int*)(w + 1202176);     // <1 KB
    float* dinv   = (float*)(w + 1203200);   // 400 KB
    int*   col    = (int*)(w + 1603584);     // 12.8 MB
    float* xws    = (float*)(w + 14403584);  // 6.4 MB
    float* out1   = (float*)(w + 20803584);  // 6.4 MB
    float* h2s    = (float*)(w + 27203584);  // 800 KB
    // total ws use: ~28 MB

    hipMemsetAsync(deg, 0, (size_t)N_NODES * sizeof(int), stream);
    k_detect<<<1, 64, 0, stream>>>(ei, flag);
    k_deg<<<N_EDGES / 256, 256, 0, stream>>>(ei, flag, deg);
    k_scanA<<<N_SCAN_BLKS, SCAN_BLK, 0, stream>>>(deg, off, bsum);
    k_scanB<<<1, 256, 0, stream>>>(bsum);
    k_scanC<<<(N_NODES + 255) / 256, 256, 0, stream>>>(off, bsum, cursor);
    k_fill<<<N_EDGES / 256, 256, 0, stream>>>(ei, flag, cursor, col);
    k_dinv<<<(N_NODES + 255) / 256, 256, 0, stream>>>(deg, dinv);
    k_gemm1<<<(N_NODES + 255) / 256, 256, 0, stream>>>(x, W1, dinv, xws);
    k_gather1<<<(N_NODES * 16) / 256, 256, 0, stream>>>(off, deg, col, dinv, xws, b1, out1);
    k_layer2<<<(N_NODES + 255) / 256, 256, 0, stream>>>(out1, W2, dinv, h2s);
    k_gather2<<<(N_NODES * 2 + 255) / 256, 256, 0, stream>>>(off, deg, col, dinv, h2s, b2, y);
}

// Round 3
// 508.630 us; speedup vs baseline: 1.0944x; 1.0944x over previous
//
#include <hip/hip_runtime.h>

#define N_NODES 100000
#define N_EDGES 3200000
#define IN_FEAT 512
#define HID 16
#define BNODES 128                        // nodes per bucket (dst >> 7)
#define NB 782                            // ceil(100000/128)
#define CHUNK 8192
#define NCHUNKS ((N_EDGES + CHUNK - 1) / CHUNK)   // 391

// ---------------------------------------------------------------------------
// Edge-index dtype hedge (int64 vs int32 storage), probed device-side.
// ---------------------------------------------------------------------------
__global__ void k_detect(const void* ei, int* flag) {
    const int* p = (const int*)ei;
    int t = threadIdx.x;                     // 64 threads = 1 wave
    bool nz = (p[2 * t + 1] != 0);
    unsigned long long m = __ballot(nz);
    if (t == 0) *flag = (m == 0ull) ? 1 : 0; // 1 => int64 storage
}

__device__ __forceinline__ int load_dst(const void* ei, int is64, int e) {
    if (is64) return (int)((const long long*)ei)[(long long)N_EDGES + e];
    return ((const int*)ei)[N_EDGES + e];
}
__device__ __forceinline__ int load_src(const void* ei, int is64, int e) {
    if (is64) return (int)((const long long*)ei)[e];
    return ((const int*)ei)[e];
}

// ---- bucket histogram ------------------------------------------------------
__global__ void k_hist(const void* ei, const int* __restrict__ flag,
                       int* __restrict__ ghist) {
    __shared__ int h[NB];
    int tid = threadIdx.x;
    int is64 = *flag;
    for (int i = tid; i < NB; i += 256) h[i] = 0;
    __syncthreads();
    for (int e = blockIdx.x * 256 + tid; e < N_EDGES; e += gridDim.x * 256)
        atomicAdd(&h[load_dst(ei, is64, e) >> 7], 1);
    __syncthreads();
    for (int i = tid; i < NB; i += 256)
        if (h[i]) atomicAdd(&ghist[i], h[i]);
}

// ---- exclusive scan over NB buckets (one block) ----------------------------
__global__ __launch_bounds__(1024)
void k_scan(const int* __restrict__ ghist, int* __restrict__ goff,
            int* __restrict__ gcursor) {
    __shared__ int s[1024];
    int tid = threadIdx.x;
    int v = (tid < NB) ? ghist[tid] : 0;
    s[tid] = v;
    __syncthreads();
    for (int o = 1; o < 1024; o <<= 1) {
        int t = (tid >= o) ? s[tid - o] : 0;
        __syncthreads();
        s[tid] += t;
        __syncthreads();
    }
    int excl = s[tid] - v;                 // tid==NB -> total (v==0 there)
    if (tid <= NB) goff[tid] = excl;
    if (tid < NB) gcursor[tid] = excl;
}

// ---- per-chunk LDS counting sort + coalesced bucketed scatter --------------
// entry = src<<7 | (dst & 127); bucket = dst>>7
__global__ __launch_bounds__(1024)
void k_sortscatter(const void* ei, const int* __restrict__ flag,
                   int* __restrict__ gcursor, unsigned* __restrict__ colp) {
    __shared__ unsigned sorted[CHUNK];     // 32 KB
    __shared__ int hist[1024];             // doubles as cursor
    __shared__ int scanL[1024];
    __shared__ int gbase[1024];
    int tid = threadIdx.x;
    int base = blockIdx.x * CHUNK;
    int chunkN = min(CHUNK, N_EDGES - base);
    int is64 = *flag;

    hist[tid] = 0;
    __syncthreads();

    unsigned ent[8];
    short bkt[8];
#pragma unroll
    for (int k = 0; k < 8; ++k) {
        int i = k * 1024 + tid;
        if (i < chunkN) {
            int e = base + i;
            int s = load_src(ei, is64, e);
            int d = load_dst(ei, is64, e);
            int b = d >> 7;
            ent[k] = ((unsigned)s << 7) | (unsigned)(d & 127);
            bkt[k] = (short)b;
            atomicAdd(&hist[b], 1);
        } else bkt[k] = -1;
    }
    __syncthreads();

    int v = hist[tid];
    scanL[tid] = v;
    __syncthreads();
    for (int o = 1; o < 1024; o <<= 1) {
        int t = (tid >= o) ? scanL[tid - o] : 0;
        __syncthreads();
        scanL[tid] += t;
        __syncthreads();
    }
    int excl = scanL[tid] - v;
    __syncthreads();
    scanL[tid] = excl;                     // scanL[NB] == chunkN automatically
    hist[tid] = 0;                         // reuse as within-bucket cursor
    __syncthreads();

#pragma unroll
    for (int k = 0; k < 8; ++k) {
        if (bkt[k] >= 0) {
            int b = bkt[k];
            int pos = atomicAdd(&hist[b], 1);
            sorted[scanL[b] + pos] = ent[k];
        }
    }
    __syncthreads();

    if (tid < NB) {
        int cnt = scanL[tid + 1] - scanL[tid];
        gbase[tid] = (cnt > 0) ? atomicAdd(&gcursor[tid], cnt) : 0;
    }
    __syncthreads();

    for (int i = tid; i < chunkN; i += 1024) {
        int lo = 0, hi = NB;               // invariant: scanL[lo] <= i < scanL[hi]
        while (hi - lo > 1) {
            int mid = (lo + hi) >> 1;
            if (scanL[mid] <= i) lo = mid; else hi = mid;
        }
        colp[gbase[lo] + (i - scanL[lo])] = sorted[i];
    }
}

// ---- degree (from bucketed entries) -> dinv --------------------------------
__global__ void k_degdinv(const int* __restrict__ goff,
                          const unsigned* __restrict__ colp,
                          float* __restrict__ dinv) {
    __shared__ int cnt[BNODES];
    int b = blockIdx.x, tid = threadIdx.x;
    if (tid < BNODES) cnt[tid] = 0;
    __syncthreads();
    int s0 = goff[b], s1 = goff[b + 1];
    for (int i = s0 + tid; i < s1; i += 256)
        atomicAdd(&cnt[colp[i] & 127], 1);
    __syncthreads();
    if (tid < BNODES) {
        int node = (b << 7) + tid;
        if (node < N_NODES) dinv[node] = rsqrtf((float)(cnt[tid] + 1));
    }
}

// ---- xws = (x @ W1) * dinv[row] -------------------------------------------
__global__ void k_gemm1(const float* __restrict__ x, const float* __restrict__ W1,
                        const float* __restrict__ dinv, float* __restrict__ xws) {
    int row = blockIdx.x * blockDim.x + threadIdx.x;
    if (row >= N_NODES) return;
    const float4* xr = (const float4*)(x + (size_t)row * IN_FEAT);
    float acc[16];
#pragma unroll
    for (int f = 0; f < 16; ++f) acc[f] = 0.f;

#pragma unroll 1
    for (int k0 = 0; k0 < IN_FEAT; k0 += 16) {
        float4 v0 = xr[k0 / 4 + 0];
        float4 v1 = xr[k0 / 4 + 1];
        float4 v2 = xr[k0 / 4 + 2];
        float4 v3 = xr[k0 / 4 + 3];
        float xv[16] = {v0.x, v0.y, v0.z, v0.w, v1.x, v1.y, v1.z, v1.w,
                        v2.x, v2.y, v2.z, v2.w, v3.x, v3.y, v3.z, v3.w};
#pragma unroll
        for (int kk = 0; kk < 16; ++kk) {
            const float* wr = W1 + (size_t)(k0 + kk) * HID;
#pragma unroll
            for (int f = 0; f < HID; ++f)
                acc[f] = fmaf(xv[kk], wr[f], acc[f]);
        }
    }
    float di = dinv[row];
    float4* xv4 = (float4*)(xws + (size_t)row * HID);
#pragma unroll
    for (int q = 0; q < 4; ++q)
        xv4[q] = make_float4(acc[4 * q] * di, acc[4 * q + 1] * di,
                             acc[4 * q + 2] * di, acc[4 * q + 3] * di);
}

// ---- layer-1 aggregation in LDS: out1 = relu(b1 + dinv*(self + sum)) ------
__global__ __launch_bounds__(512)
void k_aggr1(const int* __restrict__ goff, const unsigned* __restrict__ colp,
             const float* __restrict__ dinv, const float* __restrict__ xws,
             const float* __restrict__ b1, float* __restrict__ out1) {
    __shared__ float acc[BNODES * HID];    // 8 KB
    int b = blockIdx.x, tid = threadIdx.x;
    int f = tid & 15;
    for (int i = tid; i < BNODES * HID; i += 512) acc[i] = 0.f;
    __syncthreads();
    int s0 = goff[b], s1 = goff[b + 1];
    for (int i0 = s0; i0 < s1; i0 += 32) {
        int idx = i0 + (tid >> 4);
        if (idx < s1) {
            unsigned e = colp[idx];
            int src = e >> 7, ld = e & 127;
            atomicAdd(&acc[ld * HID + f], xws[(size_t)src * HID + f]);
        }
    }
    __syncthreads();
    float bias = b1[f];
    for (int r0 = 0; r0 < BNODES; r0 += 32) {
        int r = r0 + (tid >> 4);
        int node = (b << 7) + r;
        if (node < N_NODES) {
            float v = fmaf(dinv[node], acc[r * HID + f] + xws[(size_t)node * HID + f], bias);
            out1[(size_t)node * HID + f] = fmaxf(v, 0.f);
        }
    }
}

// ---- h2s = (out1 @ W2) * dinv ---------------------------------------------
__global__ void k_layer2(const float* __restrict__ out1, const float* __restrict__ W2,
                         const float* __restrict__ dinv, float* __restrict__ h2s) {
    int i = blockIdx.x * blockDim.x + threadIdx.x;
    if (i >= N_NODES) return;
    const float4* hv = (const float4*)(out1 + (size_t)i * HID);
    float g0 = 0.f, g1 = 0.f;
#pragma unroll
    for (int q = 0; q < 4; ++q) {
        float4 v = hv[q];
        g0 = fmaf(v.x, W2[(4 * q + 0) * 2 + 0], g0);
        g1 = fmaf(v.x, W2[(4 * q + 0) * 2 + 1], g1);
        g0 = fmaf(v.y, W2[(4 * q + 1) * 2 + 0], g0);
        g1 = fmaf(v.y, W2[(4 * q + 1) * 2 + 1], g1);
        g0 = fmaf(v.z, W2[(4 * q + 2) * 2 + 0], g0);
        g1 = fmaf(v.z, W2[(4 * q + 2) * 2 + 1], g1);
        g0 = fmaf(v.w, W2[(4 * q + 3) * 2 + 0], g0);
        g1 = fmaf(v.w, W2[(4 * q + 3) * 2 + 1], g1);
    }
    float di = dinv[i];
    ((float2*)h2s)[i] = make_float2(g0 * di, g1 * di);
}

// ---- layer-2 aggregation + log_softmax ------------------------------------
__global__ __launch_bounds__(512)
void k_aggr2(const int* __restrict__ goff, const unsigned* __restrict__ colp,
             const float* __restrict__ dinv, const float* __restrict__ h2s,
             const float* __restrict__ b2, float* __restrict__ y) {
    __shared__ float acc[BNODES * 2];
    int b = blockIdx.x, tid = threadIdx.x;
    int c = tid & 1;
    for (int i = tid; i < BNODES * 2; i += 512) acc[i] = 0.f;
    __syncthreads();
    int s0 = goff[b], s1 = goff[b + 1];
    for (int i0 = s0; i0 < s1; i0 += 256) {
        int idx = i0 + (tid >> 1);
        if (idx < s1) {
            unsigned e = colp[idx];
            int src = e >> 7, ld = e & 127;
            atomicAdd(&acc[ld * 2 + c], h2s[(size_t)src * 2 + c]);
        }
    }
    __syncthreads();
    if (tid < BNODES * 2) {
        int r = tid >> 1;
        int node = (b << 7) + r;
        if (node < N_NODES) {
            float v = fmaf(dinv[node], acc[tid] + h2s[(size_t)node * 2 + c], b2[c]);
            float o = __shfl_xor(v, 1);
            float m = fmaxf(v, o);
            float lse = m + logf(expf(v - m) + expf(o - m));
            y[(size_t)node * 2 + c] = v - lse;
        }
    }
}

extern "C" void kernel_launch(void* const* d_in, const int* in_sizes, int n_in,
                              void* d_out, int out_size, void* d_ws, size_t ws_size,
                              hipStream_t stream) {
    const float* x  = (const float*)d_in[0];
    const void*  ei = d_in[1];
    const float* W1 = (const float*)d_in[2];
    const float* b1 = (const float*)d_in[3];
    const float* W2 = (const float*)d_in[4];
    const float* b2 = (const float*)d_in[5];
    float* y = (float*)d_out;

    char* w = (char*)d_ws;
    int*      flag    = (int*)(w + 0);
    int*      ghist   = (int*)(w + 1024);       // 3128 B
    int*      goff    = (int*)(w + 8192);       // 3132 B
    int*      gcursor = (int*)(w + 16384);      // 3128 B
    float*    dinv    = (float*)(w + 24576);    // 400 KB
    unsigned* colp    = (unsigned*)(w + 425984);    // 12.8 MB
    float*    xws     = (float*)(w + 13230080);     // 6.4 MB
    float*    out1    = (float*)(w + 19631104);     // 6.4 MB
    float*    h2s     = (float*)(w + 26032128);     // 800 KB -> ends ~26.8 MB

    hipMemsetAsync(ghist, 0, NB * sizeof(int), stream);
    k_detect<<<1, 64, 0, stream>>>(ei, flag);
    k_hist<<<512, 256, 0, stream>>>(ei, flag, ghist);
    k_scan<<<1, 1024, 0, stream>>>(ghist, goff, gcursor);
    k_sortscatter<<<NCHUNKS, 1024, 0, stream>>>(ei, flag, gcursor, colp);
    k_degdinv<<<NB, 256, 0, stream>>>(goff, colp, dinv);
    k_gemm1<<<(N_NODES + 255) / 256, 256, 0, stream>>>(x, W1, dinv, xws);
    k_aggr1<<<NB, 512, 0, stream>>>(goff, colp, dinv, xws, b1, out1);
    k_layer2<<<(N_NODES + 255) / 256, 256, 0, stream>>>(out1, W2, dinv, h2s);
    k_aggr2<<<NB, 512, 0, stream>>>(goff, colp, dinv, h2s, b2, y);
}